// Round 3
// baseline (72.155 us; speedup 1.0000x reference)
//
#include <hip/hip_runtime.h>

// Problem constants
#define BB 8
#define NN 4096
#define GG 4096            // 64x64 grid cells
#define KG 32              // k-groups (point blocks per batch)
#define CS 4               // column-splits per (b,kg) tile -> 1024 blocks total
#define NCOL 16            // grid cols per block (64 / CS)
#define CHUNKS 2           // point-chunks per block
#define CPTS 64            // points per chunk
#define TPB 256
#define PITCH 72           // f16 LDS row pitch (144 B: 16B-aligned)

// -0.5/sigma^2 * log2(e), sigma=0.1
#define C2 (-72.13475204444817f)
#define STEP (2.0f / 63.0f)
#define EPS 1e-5f

typedef _Float16 f16x8 __attribute__((ext_vector_type(8)));
typedef _Float16 f16x4 __attribute__((ext_vector_type(4)));
typedef float f32x4 __attribute__((ext_vector_type(4)));

__device__ __forceinline__ float gcoord(int j) { return fmaf((float)j, STEP, -1.0f); }

// Stage 1: per (b, kgroup, colsplit) compute C(192 x 16) =
// At(192 x 128pts) @ Wx(128pts x 16) over CHUNKS chunks of 64 points,
// via f16 MFMA 16x16x32. Rows of C: [density | wy*y | wy*t] x 64 y-rows.
// PARTIAL=1: write slice into the (b,kg) ws tile; PARTIAL=0: atomicAdd into out.
// Col-split x4 gives 1024 blocks = 4 blocks/CU = 16 waves/CU (vs 1 wave/SIMD
// before) -- stage 1 was latency-bound at occupancy 4 waves/CU.
// __launch_bounds__(256,4): pin >=4 waves/SIMD so regalloc can't cap occupancy.
template <int PARTIAL>
__global__ __launch_bounds__(TPB, 4) void rbf_stage1(
    const float* __restrict__ x_c,   // (B,N,2)
    const float* __restrict__ y_c,   // (B,N)
    const float* __restrict__ t_c,   // (B,N)
    const int*  __restrict__ mask,   // (B,N) int32, nonzero = drop
    float* __restrict__ dst)
{
    __shared__ _Float16 At[192][PITCH];     // 27.6 KB: rows r=c*64+i, k=point
    __shared__ _Float16 wxT[NCOL][PITCH];   // 2.3 KB: rows = grid col (local), k=point
    __shared__ float4 pts[CHUNKS][CPTS];    // {px, py(or 1e9 if masked), y, t}

    const int cs   = blockIdx.x & (CS - 1);
    const int kg   = (blockIdx.x >> 2) & (KG - 1);
    const int b    = blockIdx.x >> 7;        // / (CS*KG)
    const int tid  = threadIdx.x;
    const int wv   = tid >> 6;       // wave 0..3
    const int lane = tid & 63;
    const int quad = lane >> 4;
    const int lr   = lane & 15;
    const int jcol = tid & 63;       // y-row (At)
    const int grp  = tid >> 6;       // 16-point group for At
    const int col16 = tid & 15;      // local grid col for wx
    const int pg    = tid >> 4;      // 4-point group for wx (0..15)
    const float gj = gcoord(jcol);
    const float gx = gcoord(cs * NCOL + col16);

    // ---- stage BOTH chunks' points up front (one global-latency window) ----
    if (tid < CHUNKS * CPTS) {
        const int c = tid >> 6, p = tid & 63;
        const int n = b * NN + (kg * CHUNKS + c) * CPTS + p;
        const float2 xv = ((const float2*)x_c)[n];
        const float py = mask[n] ? 1.0e9f : xv.y;  // masked -> wy underflows to 0
        pts[c][p] = make_float4(xv.x, py, y_c[n], t_c[n]);
    }

    f32x4 acc[3];
#pragma unroll
    for (int mt = 0; mt < 3; ++mt) acc[mt] = (f32x4){0.f, 0.f, 0.f, 0.f};

    __syncthreads();

    for (int ch = 0; ch < CHUNKS; ++ch) {
        // ---- Phase A: separable f16 weights, transposed (k-contiguous) ----
        // wy rows (shared by all col-splits; recomputed, cheap VALU):
#pragma unroll
        for (int h = 0; h < 2; ++h) {
            f16x8 ve, vy, vt;
#pragma unroll
            for (int e = 0; e < 8; ++e) {
                const float4 P = pts[ch][grp * 16 + h * 8 + e]; // wave-uniform bcast
                const float dy = P.y - gj;
                const float ex = exp2f(C2 * dy * dy);
                ve[e] = (_Float16)ex;
                vy[e] = (_Float16)(ex * P.z);
                vt[e] = (_Float16)(ex * P.w);
            }
            const int o = grp * 16 + h * 8;
            *(f16x8*)&At[jcol][o]       = ve;
            *(f16x8*)&At[64 + jcol][o]  = vy;
            *(f16x8*)&At[128 + jcol][o] = vt;
        }
        // wx: only this block's 16 cols; 4 points per thread
        {
            f16x4 vx;
#pragma unroll
            for (int e = 0; e < 4; ++e) {
                const float4 P = pts[ch][pg * 4 + e];
                const float dx = P.x - gx;
                vx[e] = (_Float16)exp2f(C2 * dx * dx);
            }
            *(f16x4*)&wxT[col16][pg * 4] = vx;
        }
        __syncthreads();

        // ---- Phase B: 6 MFMAs/wave. Wave owns rows [wv*48, wv*48+48) x 16 cols
        // A-frag: A[m=lr][k=quad*8+j]; B-frag: B[k=quad*8+j][n=lr]; both 1x b128.
#pragma unroll
        for (int ks = 0; ks < 2; ++ks) {
            const int kb = ks * 32 + quad * 8;
            f16x8 a[3];
#pragma unroll
            for (int mt = 0; mt < 3; ++mt)
                a[mt] = *(const f16x8*)&At[wv * 48 + mt * 16 + lr][kb];
            const f16x8 bf = *(const f16x8*)&wxT[lr][kb];
#pragma unroll
            for (int mt = 0; mt < 3; ++mt)
                acc[mt] = __builtin_amdgcn_mfma_f32_16x16x32_f16(
                    a[mt], bf, acc[mt], 0, 0, 0);
        }
        if (ch + 1 < CHUNKS) __syncthreads();   // B(ch) before A(ch+1) rewrites LDS
    }

    // ---- epilogue: C/D layout col=lr, row=quad*4+reg ----
    if (PARTIAL) {
        float* tb = dst + ((size_t)(b * KG + kg) * 192) * 64;
#pragma unroll
        for (int mt = 0; mt < 3; ++mt)
#pragma unroll
            for (int r = 0; r < 4; ++r) {
                const int row = wv * 48 + mt * 16 + quad * 4 + r;
                tb[row * 64 + cs * NCOL + lr] = acc[mt][r];
            }
    } else {
        float* ob = dst + (size_t)b * 3 * GG;
#pragma unroll
        for (int mt = 0; mt < 3; ++mt)
#pragma unroll
            for (int r = 0; r < 4; ++r) {
                const int row = wv * 48 + mt * 16 + quad * 4 + r;
                atomicAdd(ob + row * 64 + cs * NCOL + lr, acc[mt][r]);
            }
    }
}

// Stage 2: sum KG partials per cell + normalize. 2 threads per cell (k-split),
// combined via shfl_xor. 256 blocks x 256 threads (was 128 blocks, 0.5/CU).
// All 48 loads hoisted into one fully-unrolled batch for max MLP.
__global__ __launch_bounds__(256) void rbf_reduce(
    const float* __restrict__ ws, float* __restrict__ out)
{
    const int idx  = blockIdx.x * 256 + threadIdx.x;   // over 2*B*G
    const int kh   = idx & 1;
    const int cell = idx >> 1;
    const int b = cell >> 12;
    const int g = cell & (GG - 1);
    const float* p = ws + ((size_t)b * KG * 3) * GG + (size_t)kh * (KG / 2) * 3 * GG + g;
    float den = 0.f, sy = 0.f, st = 0.f;
#pragma unroll
    for (int k = 0; k < KG / 2; ++k) {
        const float* q = p + (size_t)k * 3 * GG;
        den += q[0];
        sy  += q[GG];
        st  += q[2 * GG];
    }
    den += __shfl_xor(den, 1, 64);
    sy  += __shfl_xor(sy, 1, 64);
    st  += __shfl_xor(st, 1, 64);
    if (kh == 0) {
        float* ob = out + (size_t)b * 3 * GG;
        const float inv = 1.0f / (den + EPS);
        ob[g]          = den;
        ob[GG + g]     = sy * inv;
        ob[2 * GG + g] = st * inv;
    }
}

// Fallback normalize (atomic path).
__global__ __launch_bounds__(256) void rbf_norm(float* __restrict__ out)
{
    const int idx = blockIdx.x * 256 + threadIdx.x;
    const int b = idx >> 12;
    const int g = idx & (GG - 1);
    float* ob = out + (size_t)b * 3 * GG;
    const float inv = 1.0f / (ob[g] + EPS);
    ob[GG + g]     *= inv;
    ob[2 * GG + g] *= inv;
}

extern "C" void kernel_launch(void* const* d_in, const int* in_sizes, int n_in,
                              void* d_out, int out_size, void* d_ws, size_t ws_size,
                              hipStream_t stream) {
    const float* x_c  = (const float*)d_in[0];
    const float* y_c  = (const float*)d_in[1];
    const float* t_c  = (const float*)d_in[2];
    const int*   mask = (const int*)d_in[3];
    float* out = (float*)d_out;
    float* ws  = (float*)d_ws;

    const size_t need = (size_t)BB * KG * 192 * 64 * sizeof(float); // 12.6 MB

    if (ws_size >= need) {
        rbf_stage1<1><<<BB * KG * CS, TPB, 0, stream>>>(x_c, y_c, t_c, mask, ws);
        rbf_reduce<<<(BB * GG * 2) / 256, 256, 0, stream>>>(ws, out);
    } else {
        hipMemsetAsync(out, 0, (size_t)BB * 3 * GG * sizeof(float), stream);
        rbf_stage1<0><<<BB * KG * CS, TPB, 0, stream>>>(x_c, y_c, t_c, mask, out);
        rbf_norm<<<(BB * GG) / 256, 256, 0, stream>>>(out);
    }
}